// Round 15
// baseline (202.054 us; speedup 1.0000x reference)
//
#include <hip/hip_runtime.h>
#include <hip/hip_bf16.h>

typedef unsigned short u16;
typedef unsigned int u32;
typedef __attribute__((ext_vector_type(8))) short short8;
typedef __attribute__((ext_vector_type(4))) short s16x4;
typedef __attribute__((ext_vector_type(4))) float f32x4;
typedef __attribute__((ext_vector_type(4))) u32 u32v4;

__device__ __forceinline__ u16 f2bf(float f) {
    u32 u = __float_as_uint(f);
    return (u16)((u + 0x7FFFu + ((u >> 16) & 1u)) >> 16);   // RNE
}
__device__ __forceinline__ u32 pack2bf(float a, float b) {
    __hip_bfloat162 h = __float22bfloat162_rn(float2{a, b});
    return *reinterpret_cast<u32*>(&h);
}
#if __has_builtin(__builtin_amdgcn_exp2f)
#define EXP2(x) __builtin_amdgcn_exp2f(x)
#else
#define EXP2(x) exp2f(x)
#endif

__device__ __forceinline__ void gload16(const void* g, void* s) {
    __builtin_amdgcn_global_load_lds(
        (const __attribute__((address_space(1))) void*)g,
        (__attribute__((address_space(3))) void*)s, 16, 0, 0);
}

// ---------------- fused cast: 7 fp32 tensors -> bf16 ----------------
__global__ __launch_bounds__(256) void cast_all_kernel(
    const float* __restrict__ s0, const float* __restrict__ s1, const float* __restrict__ s2,
    const float* __restrict__ s3, const float* __restrict__ s4, const float* __restrict__ s5,
    const float* __restrict__ s6,
    u16* __restrict__ d0, u16* __restrict__ d1, u16* __restrict__ d2,
    u16* __restrict__ d3, u16* __restrict__ d4, u16* __restrict__ d5,
    u16* __restrict__ d6, int nBig, int nSmall)
{
    const int y = blockIdx.y;
    const float* s = y == 0 ? s0 : (y == 1 ? s1 : (y == 2 ? s2 : (y == 3 ? s3 : (y == 4 ? s4 : (y == 5 ? s5 : s6)))));
    u16* d = y == 0 ? d0 : (y == 1 ? d1 : (y == 2 ? d2 : (y == 3 ? d3 : (y == 4 ? d4 : (y == 5 ? d5 : d6)))));
    const int n = (y < 3) ? nBig : nSmall;
    int i = (blockIdx.x * 256 + threadIdx.x) * 4;
    const int stride = gridDim.x * 256 * 4;
    for (; i < n; i += stride) {
        float4 v = *(const float4*)(s + i);
        uint2 t;
        t.x = pack2bf(v.x, v.y);
        t.y = pack2bf(v.z, v.w);
        *(uint2*)(d + i) = t;
    }
}

// ---------------- fused QKV GEMM (R11/R13 form, unchanged) ----------------
__global__ __launch_bounds__(256) void qkv_gemm(
    const u16* __restrict__ Xq, const u16* __restrict__ Xk, const u16* __restrict__ Xv,
    const u16* __restrict__ Wq, const u16* __restrict__ Wk, const u16* __restrict__ Wv,
    const float* __restrict__ qb, const float* __restrict__ kb, const float* __restrict__ vb,
    u16* __restrict__ Qo, u16* __restrict__ Ko, u16* __restrict__ Vo)
{
    constexpr int N = 1024, K = 1024;
    __shared__ __align__(16) u16 Asm[2][4096];
    __shared__ __align__(16) u16 Bsm[2][4096];
    const int z = blockIdx.z;
    const u16* A = z == 0 ? Xq : (z == 1 ? Xk : Xv);
    const u16* W = z == 0 ? Wq : (z == 1 ? Wk : Wv);
    const float* bias = z == 0 ? qb : (z == 1 ? kb : vb);

    const int tid = threadIdx.x;
    const int wid = tid >> 6;
    const int lane = tid & 63;
    const int r15 = lane & 15, g = lane >> 4;
    const int fb = blockIdx.y * 8 + blockIdx.x;
    const int lsw = (fb & 7) * 32 + (fb >> 3);
    const int m0 = (lsw >> 3) * 128, n0 = (lsw & 7) * 128;
    const int wr = wid >> 1, wc = wid & 1;

    f32x4 acc[4][4];
#pragma unroll
    for (int i = 0; i < 4; ++i)
#pragma unroll
        for (int j = 0; j < 4; ++j) acc[i][j] = (f32x4){0.f, 0.f, 0.f, 0.f};

    const int idx0 = tid, idx1 = tid + 256;
    const size_t aoff0 = (size_t)(m0 + (idx0 >> 2)) * K + (idx0 & 3) * 8;
    const size_t aoff1 = (size_t)(m0 + (idx1 >> 2)) * K + (idx1 & 3) * 8;
    const size_t boff0 = (size_t)(n0 + (idx0 >> 2)) * K + (idx0 & 3) * 8;
    const size_t boff1 = (size_t)(n0 + (idx1 >> 2)) * K + (idx1 & 3) * 8;

    auto STAGE = [&](int buf, int kt) {
        gload16(A + aoff0 + kt, &Asm[buf][wid * 512]);
        gload16(A + aoff1 + kt, &Asm[buf][2048 + wid * 512]);
        gload16(W + boff0 + kt, &Bsm[buf][wid * 512]);
        gload16(W + boff1 + kt, &Bsm[buf][2048 + wid * 512]);
    };

    STAGE(0, 0);
    __syncthreads();
    for (int t = 0; t < 32; ++t) {
        const int buf = t & 1;
        if (t < 31) STAGE(buf ^ 1, (t + 1) * 32);
        short8 af[4], bfr[4];
#pragma unroll
        for (int i = 0; i < 4; ++i) {
            af[i]  = *(const short8*)(&Asm[buf][0] + (wr * 64 + i * 16 + r15) * 32 + g * 8);
            bfr[i] = *(const short8*)(&Bsm[buf][0] + (wc * 64 + i * 16 + r15) * 32 + g * 8);
        }
#pragma unroll
        for (int i = 0; i < 4; ++i)
#pragma unroll
            for (int j = 0; j < 4; ++j)
                acc[i][j] = __builtin_amdgcn_mfma_f32_16x16x32_bf16(af[i], bfr[j], acc[i][j], 0, 0, 0);
        __syncthreads();
    }

    const float scale = (z == 0) ? 0.125f * 1.4426950408889634f : 1.0f;
    u16* ob = z == 0 ? Qo : (z == 1 ? Ko : Vo);
#pragma unroll
    for (int i = 0; i < 4; ++i) {
        const int mbase = m0 + wr * 64 + i * 16 + g * 4;
#pragma unroll
        for (int j = 0; j < 4; ++j) {
            const int n = n0 + wc * 64 + j * 16 + r15;
            const float bb = bias[n];
            if (z < 2) {
#pragma unroll
                for (int r = 0; r < 4; ++r)
                    ob[(size_t)(mbase + r) * N + n] = f2bf((acc[i][j][r] + bb) * scale);
            } else {
                const int b_ = mbase >> 11, s_ = mbase & 2047;
                const int blk = (s_ >> 2) & 7;
                const int pb = ((blk & 3) << 1) | (blk >> 2);
                const int s_new = (s_ & ~31) | (pb << 2);
                s16x4 pk;
#pragma unroll
                for (int r = 0; r < 4; ++r) pk[r] = (short)f2bf(acc[i][j][r] + bb);
                *(s16x4*)(ob + ((size_t)b_ << 21) + (size_t)n * 2048 + s_new) = pk;
            }
        }
    }
}

// ---------------- O projection GEMM (R11/R13 form, unchanged) ----------------
__global__ __launch_bounds__(256) void o_gemm(
    const u16* __restrict__ A, const u16* __restrict__ W,
    const float* __restrict__ bias, float* __restrict__ outp)
{
    constexpr int N = 1024, K = 1024;
    __shared__ __align__(16) u16 Asm[2][4096];
    __shared__ __align__(16) u16 Bsm[2][4096];
    const int tid = threadIdx.x;
    const int wid = tid >> 6;
    const int lane = tid & 63;
    const int r15 = lane & 15, g = lane >> 4;
    const int fb = blockIdx.y * 8 + blockIdx.x;
    const int lsw = (fb & 7) * 32 + (fb >> 3);
    const int m0 = (lsw >> 3) * 128, n0 = (lsw & 7) * 128;
    const int wr = wid >> 1, wc = wid & 1;

    f32x4 acc[4][4];
#pragma unroll
    for (int i = 0; i < 4; ++i)
#pragma unroll
        for (int j = 0; j < 4; ++j) acc[i][j] = (f32x4){0.f, 0.f, 0.f, 0.f};

    const int idx0 = tid, idx1 = tid + 256;
    const size_t aoff0 = (size_t)(m0 + (idx0 >> 2)) * K + (idx0 & 3) * 8;
    const size_t aoff1 = (size_t)(m0 + (idx1 >> 2)) * K + (idx1 & 3) * 8;
    const size_t boff0 = (size_t)(n0 + (idx0 >> 2)) * K + (idx0 & 3) * 8;
    const size_t boff1 = (size_t)(n0 + (idx1 >> 2)) * K + (idx1 & 3) * 8;

    auto STAGE = [&](int buf, int kt) {
        gload16(A + aoff0 + kt, &Asm[buf][wid * 512]);
        gload16(A + aoff1 + kt, &Asm[buf][2048 + wid * 512]);
        gload16(W + boff0 + kt, &Bsm[buf][wid * 512]);
        gload16(W + boff1 + kt, &Bsm[buf][2048 + wid * 512]);
    };

    STAGE(0, 0);
    __syncthreads();
    for (int t = 0; t < 32; ++t) {
        const int buf = t & 1;
        if (t < 31) STAGE(buf ^ 1, (t + 1) * 32);
        short8 af[4], bfr[4];
#pragma unroll
        for (int i = 0; i < 4; ++i) {
            af[i]  = *(const short8*)(&Asm[buf][0] + (wr * 64 + i * 16 + r15) * 32 + g * 8);
            bfr[i] = *(const short8*)(&Bsm[buf][0] + (wc * 64 + i * 16 + r15) * 32 + g * 8);
        }
#pragma unroll
        for (int i = 0; i < 4; ++i)
#pragma unroll
            for (int j = 0; j < 4; ++j)
                acc[i][j] = __builtin_amdgcn_mfma_f32_16x16x32_bf16(af[i], bfr[j], acc[i][j], 0, 0, 0);
        __syncthreads();
    }

#pragma unroll
    for (int i = 0; i < 4; ++i) {
        const int mbase = m0 + wr * 64 + i * 16 + g * 4;
#pragma unroll
        for (int j = 0; j < 4; ++j) {
            const int n = n0 + wc * 64 + j * 16 + r15;
            const float bb = bias[n];
#pragma unroll
            for (int r = 0; r < 4; ++r)
                outp[(size_t)(mbase + r) * N + n] = acc[i][j][r] + bb;
        }
    }
}

// ---------------- flash attention v9: no LDS, no barriers, builtin exp2 ----------
// 2048 blocks x 64 threads (1 wave), 32 q/wave. K and V read directly global->reg
// (L2-resident: 4 bh/XCD = 2MB < 4MB L2). Plain __launch_bounds__(64) (no min-waves
// arg — suspect in R12/R14 failures) and builtin exp2 (hazard-safe, vs inline asm).
// P in registers (permuted k-order baked into Vt). ones-MFMA lsum.
__global__ __launch_bounds__(64) void attn_kernel(
    const u16* __restrict__ Q, const u16* __restrict__ Kb,
    const u16* __restrict__ Vt, u16* __restrict__ Mo)
{
    const int lane = threadIdx.x;
    const int r15 = lane & 15, g = lane >> 4;
    // XCD swizzle: 2048 blocks; each XCD serves 4 consecutive (b,h)
    const int bid = blockIdx.x;
    const int l = (bid & 7) * 256 + (bid >> 3);
    const int bh = l >> 6;
    const int b = bh >> 4, h = bh & 15;
    const int q0 = (l & 63) * 32;

    // persistent Q fragments: q = q0 + qt*16 + r15, d = f*32 + g*8
    const u16* Qbase = Q + ((size_t)b * 2048 + q0) * 1024 + h * 64;
    short8 qf[2][2];
#pragma unroll
    for (int qt = 0; qt < 2; ++qt)
#pragma unroll
        for (int f = 0; f < 2; ++f)
            qf[qt][f] = *(const short8*)(Qbase + (size_t)(qt * 16 + r15) * 1024 + f * 32 + g * 8);

    // base pointers; per-iter offsets are compile-time-scaled t
    const u16* Kp = Kb + ((size_t)b * 2048 + r15) * 1024 + h * 64 + g * 8;
    const u16* Vp = Vt + ((size_t)b << 21) + (size_t)(h * 64 + r15) * 2048 + g * 8;

    f32x4 acc[2][4];
#pragma unroll
    for (int qt = 0; qt < 2; ++qt)
#pragma unroll
        for (int d4 = 0; d4 < 4; ++d4) acc[qt][d4] = (f32x4){0.f, 0.f, 0.f, 0.f};
    f32x4 accl[2] = {(f32x4){0.f, 0.f, 0.f, 0.f}, (f32x4){0.f, 0.f, 0.f, 0.f}};
    const short8 vone = {0x3F80, 0x3F80, 0x3F80, 0x3F80, 0x3F80, 0x3F80, 0x3F80, 0x3F80};

    for (int t = 0; t < 32; ++t) {
        const u16* Kt = Kp + (size_t)t * 65536;   // + t*64 k-rows
        const u16* Vc = Vp + t * 64;              // + t*64 position-cols
        short8 kf[4][2], vf[4][2];
#pragma unroll
        for (int kt = 0; kt < 4; ++kt) {
            kf[kt][0] = *(const short8*)(Kt + kt * 16384);        // row kt*16+r15, d g*8
            kf[kt][1] = *(const short8*)(Kt + kt * 16384 + 32);   // d 32+g*8
        }
#pragma unroll
        for (int d4 = 0; d4 < 4; ++d4) {
            vf[d4][0] = *(const short8*)(Vc + d4 * 32768);        // row d4*16+r15, pos g*8
            vf[d4][1] = *(const short8*)(Vc + d4 * 32768 + 32);   // pos 32+g*8
        }

        f32x4 st[2][4];
#pragma unroll
        for (int qt = 0; qt < 2; ++qt)
#pragma unroll
            for (int kt = 0; kt < 4; ++kt) {
                f32x4 zz = (f32x4){0.f, 0.f, 0.f, 0.f};
                zz = __builtin_amdgcn_mfma_f32_16x16x32_bf16(kf[kt][0], qf[qt][0], zz, 0, 0, 0);
                zz = __builtin_amdgcn_mfma_f32_16x16x32_bf16(kf[kt][1], qf[qt][1], zz, 0, 0, 0);
                st[qt][kt] = zz;
            }

        u32v4 pA[2], pB[2];
#pragma unroll
        for (int qt = 0; qt < 2; ++qt) {
#pragma unroll
            for (int kt = 0; kt < 4; ++kt) {
                float e0 = EXP2(st[qt][kt][0]);
                float e1 = EXP2(st[qt][kt][1]);
                float e2 = EXP2(st[qt][kt][2]);
                float e3 = EXP2(st[qt][kt][3]);
                u32 lo = pack2bf(e0, e1);
                u32 hi = pack2bf(e2, e3);
                if (kt < 2) { pA[qt][kt * 2] = lo; pA[qt][kt * 2 + 1] = hi; }
                else        { pB[qt][(kt - 2) * 2] = lo; pB[qt][(kt - 2) * 2 + 1] = hi; }
            }
        }

        accl[0] = __builtin_amdgcn_mfma_f32_16x16x32_bf16(vone, __builtin_bit_cast(short8, pA[0]), accl[0], 0, 0, 0);
        accl[0] = __builtin_amdgcn_mfma_f32_16x16x32_bf16(vone, __builtin_bit_cast(short8, pB[0]), accl[0], 0, 0, 0);
        accl[1] = __builtin_amdgcn_mfma_f32_16x16x32_bf16(vone, __builtin_bit_cast(short8, pA[1]), accl[1], 0, 0, 0);
        accl[1] = __builtin_amdgcn_mfma_f32_16x16x32_bf16(vone, __builtin_bit_cast(short8, pB[1]), accl[1], 0, 0, 0);

#pragma unroll
        for (int d4 = 0; d4 < 4; ++d4) {
            acc[0][d4] = __builtin_amdgcn_mfma_f32_16x16x32_bf16(vf[d4][0], __builtin_bit_cast(short8, pA[0]), acc[0][d4], 0, 0, 0);
            acc[0][d4] = __builtin_amdgcn_mfma_f32_16x16x32_bf16(vf[d4][1], __builtin_bit_cast(short8, pB[0]), acc[0][d4], 0, 0, 0);
            acc[1][d4] = __builtin_amdgcn_mfma_f32_16x16x32_bf16(vf[d4][0], __builtin_bit_cast(short8, pA[1]), acc[1][d4], 0, 0, 0);
            acc[1][d4] = __builtin_amdgcn_mfma_f32_16x16x32_bf16(vf[d4][1], __builtin_bit_cast(short8, pB[1]), acc[1][d4], 0, 0, 0);
        }
    }

#pragma unroll
    for (int qt = 0; qt < 2; ++qt) {
        const float inv = 1.f / accl[qt][0];
        const size_t orow = ((size_t)b * 2048 + q0 + qt * 16 + r15) * 1024 + h * 64;
#pragma unroll
        for (int d4 = 0; d4 < 4; ++d4) {
            uint2 o;
            o.x = pack2bf(acc[qt][d4][0] * inv, acc[qt][d4][1] * inv);
            o.y = pack2bf(acc[qt][d4][2] * inv, acc[qt][d4][3] * inv);
            *(uint2*)(Mo + orow + d4 * 16 + g * 4) = o;
        }
    }
}

extern "C" void kernel_launch(void* const* d_in, const int* in_sizes, int n_in,
                              void* d_out, int out_size, void* d_ws, size_t ws_size,
                              hipStream_t stream) {
    (void)in_sizes; (void)n_in; (void)out_size; (void)ws_size;
    const float* query = (const float*)d_in[0];
    const float* key   = (const float*)d_in[1];
    const float* value = (const float*)d_in[2];
    const float* q_w = (const float*)d_in[3];
    const float* q_b = (const float*)d_in[4];
    const float* k_w = (const float*)d_in[5];
    const float* k_b = (const float*)d_in[6];
    const float* v_w = (const float*)d_in[7];
    const float* v_b = (const float*)d_in[8];
    const float* o_w = (const float*)d_in[9];
    const float* o_b = (const float*)d_in[10];

    const size_t NE = (size_t)4096 * 1024;
    const size_t MW = (size_t)1024 * 1024;
    u16* w = (u16*)d_ws;
    u16* Xq = w;
    u16* Xk = Xq + NE;
    u16* Xv = Xk + NE;
    u16* Wq = Xv + NE;
    u16* Wk = Wq + MW;
    u16* Wv = Wk + MW;
    u16* Wo = Wv + MW;
    u16* Qb = Wo + MW;
    u16* Kb = Qb + NE;
    u16* Vt = Kb + NE;      // [B][1024 d][2048 s], s permuted within 32-blocks
    u16* Mo = Vt + NE;

    cast_all_kernel<<<dim3(2048, 7), 256, 0, stream>>>(
        query, key, value, q_w, k_w, v_w, o_w,
        Xq, Xk, Xv, Wq, Wk, Wv, Wo, (int)NE, (int)MW);
    qkv_gemm<<<dim3(8, 32, 3), 256, 0, stream>>>(
        Xq, Xk, Xv, Wq, Wk, Wv, q_b, k_b, v_b, Qb, Kb, Vt);
    attn_kernel<<<dim3(2048), 64, 0, stream>>>(Qb, Kb, Vt, Mo);
    o_gemm<<<dim3(8, 32), 256, 0, stream>>>(Mo, Wo, o_b, (float*)d_out);
}

// Round 16
// 165.318 us; speedup vs baseline: 1.2222x; 1.2222x over previous
//
#include <hip/hip_runtime.h>
#include <hip/hip_bf16.h>

typedef unsigned short u16;
typedef unsigned int u32;
typedef __attribute__((ext_vector_type(8))) short short8;
typedef __attribute__((ext_vector_type(4))) short s16x4;
typedef __attribute__((ext_vector_type(4))) float f32x4;
typedef __attribute__((ext_vector_type(4))) u32 u32v4;

__device__ __forceinline__ u16 f2bf(float f) {
    u32 u = __float_as_uint(f);
    return (u16)((u + 0x7FFFu + ((u >> 16) & 1u)) >> 16);   // RNE
}
__device__ __forceinline__ u32 pack2bf(float a, float b) {
    __hip_bfloat162 h = __float22bfloat162_rn(float2{a, b});
    return *reinterpret_cast<u32*>(&h);
}
#if __has_builtin(__builtin_amdgcn_exp2f)
#define EXP2(x) __builtin_amdgcn_exp2f(x)
#else
#define EXP2(x) exp2f(x)
#endif

__device__ __forceinline__ void gload16(const void* g, void* s) {
    __builtin_amdgcn_global_load_lds(
        (const __attribute__((address_space(1))) void*)g,
        (__attribute__((address_space(3))) void*)s, 16, 0, 0);
}

// single-wave pipeline gates (R9-proven skeleton; no barriers in attn):
#define VMW8() asm volatile("s_waitcnt vmcnt(8)" ::: "memory")
#define VMW0() asm volatile("s_waitcnt vmcnt(0)" ::: "memory")
#define LGK0() asm volatile("s_waitcnt lgkmcnt(0)" ::: "memory")

// ---------------- fused cast: 7 fp32 tensors -> bf16 ----------------
__global__ __launch_bounds__(256) void cast_all_kernel(
    const float* __restrict__ s0, const float* __restrict__ s1, const float* __restrict__ s2,
    const float* __restrict__ s3, const float* __restrict__ s4, const float* __restrict__ s5,
    const float* __restrict__ s6,
    u16* __restrict__ d0, u16* __restrict__ d1, u16* __restrict__ d2,
    u16* __restrict__ d3, u16* __restrict__ d4, u16* __restrict__ d5,
    u16* __restrict__ d6, int nBig, int nSmall)
{
    const int y = blockIdx.y;
    const float* s = y == 0 ? s0 : (y == 1 ? s1 : (y == 2 ? s2 : (y == 3 ? s3 : (y == 4 ? s4 : (y == 5 ? s5 : s6)))));
    u16* d = y == 0 ? d0 : (y == 1 ? d1 : (y == 2 ? d2 : (y == 3 ? d3 : (y == 4 ? d4 : (y == 5 ? d5 : d6)))));
    const int n = (y < 3) ? nBig : nSmall;
    int i = (blockIdx.x * 256 + threadIdx.x) * 4;
    const int stride = gridDim.x * 256 * 4;
    for (; i < n; i += stride) {
        float4 v = *(const float4*)(s + i);
        uint2 t;
        t.x = pack2bf(v.x, v.y);
        t.y = pack2bf(v.z, v.w);
        *(uint2*)(d + i) = t;
    }
}

// ---------------- fused QKV GEMM (R11 form, unchanged/passing) ----------------
__global__ __launch_bounds__(256) void qkv_gemm(
    const u16* __restrict__ Xq, const u16* __restrict__ Xk, const u16* __restrict__ Xv,
    const u16* __restrict__ Wq, const u16* __restrict__ Wk, const u16* __restrict__ Wv,
    const float* __restrict__ qb, const float* __restrict__ kb, const float* __restrict__ vb,
    u16* __restrict__ Qo, u16* __restrict__ Ko, u16* __restrict__ Vo)
{
    constexpr int N = 1024, K = 1024;
    __shared__ __align__(16) u16 Asm[2][4096];
    __shared__ __align__(16) u16 Bsm[2][4096];
    const int z = blockIdx.z;
    const u16* A = z == 0 ? Xq : (z == 1 ? Xk : Xv);
    const u16* W = z == 0 ? Wq : (z == 1 ? Wk : Wv);
    const float* bias = z == 0 ? qb : (z == 1 ? kb : vb);

    const int tid = threadIdx.x;
    const int wid = tid >> 6;
    const int lane = tid & 63;
    const int r15 = lane & 15, g = lane >> 4;
    const int fb = blockIdx.y * 8 + blockIdx.x;
    const int lsw = (fb & 7) * 32 + (fb >> 3);
    const int m0 = (lsw >> 3) * 128, n0 = (lsw & 7) * 128;
    const int wr = wid >> 1, wc = wid & 1;

    f32x4 acc[4][4];
#pragma unroll
    for (int i = 0; i < 4; ++i)
#pragma unroll
        for (int j = 0; j < 4; ++j) acc[i][j] = (f32x4){0.f, 0.f, 0.f, 0.f};

    const int idx0 = tid, idx1 = tid + 256;
    const size_t aoff0 = (size_t)(m0 + (idx0 >> 2)) * K + (idx0 & 3) * 8;
    const size_t aoff1 = (size_t)(m0 + (idx1 >> 2)) * K + (idx1 & 3) * 8;
    const size_t boff0 = (size_t)(n0 + (idx0 >> 2)) * K + (idx0 & 3) * 8;
    const size_t boff1 = (size_t)(n0 + (idx1 >> 2)) * K + (idx1 & 3) * 8;

    auto STAGE = [&](int buf, int kt) {
        gload16(A + aoff0 + kt, &Asm[buf][wid * 512]);
        gload16(A + aoff1 + kt, &Asm[buf][2048 + wid * 512]);
        gload16(W + boff0 + kt, &Bsm[buf][wid * 512]);
        gload16(W + boff1 + kt, &Bsm[buf][2048 + wid * 512]);
    };

    STAGE(0, 0);
    __syncthreads();
    for (int t = 0; t < 32; ++t) {
        const int buf = t & 1;
        if (t < 31) STAGE(buf ^ 1, (t + 1) * 32);
        short8 af[4], bfr[4];
#pragma unroll
        for (int i = 0; i < 4; ++i) {
            af[i]  = *(const short8*)(&Asm[buf][0] + (wr * 64 + i * 16 + r15) * 32 + g * 8);
            bfr[i] = *(const short8*)(&Bsm[buf][0] + (wc * 64 + i * 16 + r15) * 32 + g * 8);
        }
#pragma unroll
        for (int i = 0; i < 4; ++i)
#pragma unroll
            for (int j = 0; j < 4; ++j)
                acc[i][j] = __builtin_amdgcn_mfma_f32_16x16x32_bf16(af[i], bfr[j], acc[i][j], 0, 0, 0);
        __syncthreads();
    }

    const float scale = (z == 0) ? 0.125f * 1.4426950408889634f : 1.0f;
    u16* ob = z == 0 ? Qo : (z == 1 ? Ko : Vo);
#pragma unroll
    for (int i = 0; i < 4; ++i) {
        const int mbase = m0 + wr * 64 + i * 16 + g * 4;
#pragma unroll
        for (int j = 0; j < 4; ++j) {
            const int n = n0 + wc * 64 + j * 16 + r15;
            const float bb = bias[n];
            if (z < 2) {
#pragma unroll
                for (int r = 0; r < 4; ++r)
                    ob[(size_t)(mbase + r) * N + n] = f2bf((acc[i][j][r] + bb) * scale);
            } else {
                const int b_ = mbase >> 11, s_ = mbase & 2047;
                const int blk = (s_ >> 2) & 7;
                const int pb = ((blk & 3) << 1) | (blk >> 2);
                const int s_new = (s_ & ~31) | (pb << 2);
                s16x4 pk;
#pragma unroll
                for (int r = 0; r < 4; ++r) pk[r] = (short)f2bf(acc[i][j][r] + bb);
                *(s16x4*)(ob + ((size_t)b_ << 21) + (size_t)n * 2048 + s_new) = pk;
            }
        }
    }
}

// ---------------- O projection GEMM (R11 form, unchanged/passing) ----------------
__global__ __launch_bounds__(256) void o_gemm(
    const u16* __restrict__ A, const u16* __restrict__ W,
    const float* __restrict__ bias, float* __restrict__ outp)
{
    constexpr int N = 1024, K = 1024;
    __shared__ __align__(16) u16 Asm[2][4096];
    __shared__ __align__(16) u16 Bsm[2][4096];
    const int tid = threadIdx.x;
    const int wid = tid >> 6;
    const int lane = tid & 63;
    const int r15 = lane & 15, g = lane >> 4;
    const int fb = blockIdx.y * 8 + blockIdx.x;
    const int lsw = (fb & 7) * 32 + (fb >> 3);
    const int m0 = (lsw >> 3) * 128, n0 = (lsw & 7) * 128;
    const int wr = wid >> 1, wc = wid & 1;

    f32x4 acc[4][4];
#pragma unroll
    for (int i = 0; i < 4; ++i)
#pragma unroll
        for (int j = 0; j < 4; ++j) acc[i][j] = (f32x4){0.f, 0.f, 0.f, 0.f};

    const int idx0 = tid, idx1 = tid + 256;
    const size_t aoff0 = (size_t)(m0 + (idx0 >> 2)) * K + (idx0 & 3) * 8;
    const size_t aoff1 = (size_t)(m0 + (idx1 >> 2)) * K + (idx1 & 3) * 8;
    const size_t boff0 = (size_t)(n0 + (idx0 >> 2)) * K + (idx0 & 3) * 8;
    const size_t boff1 = (size_t)(n0 + (idx1 >> 2)) * K + (idx1 & 3) * 8;

    auto STAGE = [&](int buf, int kt) {
        gload16(A + aoff0 + kt, &Asm[buf][wid * 512]);
        gload16(A + aoff1 + kt, &Asm[buf][2048 + wid * 512]);
        gload16(W + boff0 + kt, &Bsm[buf][wid * 512]);
        gload16(W + boff1 + kt, &Bsm[buf][2048 + wid * 512]);
    };

    STAGE(0, 0);
    __syncthreads();
    for (int t = 0; t < 32; ++t) {
        const int buf = t & 1;
        if (t < 31) STAGE(buf ^ 1, (t + 1) * 32);
        short8 af[4], bfr[4];
#pragma unroll
        for (int i = 0; i < 4; ++i) {
            af[i]  = *(const short8*)(&Asm[buf][0] + (wr * 64 + i * 16 + r15) * 32 + g * 8);
            bfr[i] = *(const short8*)(&Bsm[buf][0] + (wc * 64 + i * 16 + r15) * 32 + g * 8);
        }
#pragma unroll
        for (int i = 0; i < 4; ++i)
#pragma unroll
            for (int j = 0; j < 4; ++j)
                acc[i][j] = __builtin_amdgcn_mfma_f32_16x16x32_bf16(af[i], bfr[j], acc[i][j], 0, 0, 0);
        __syncthreads();
    }

#pragma unroll
    for (int i = 0; i < 4; ++i) {
        const int mbase = m0 + wr * 64 + i * 16 + g * 4;
#pragma unroll
        for (int j = 0; j < 4; ++j) {
            const int n = n0 + wc * 64 + j * 16 + r15;
            const float bb = bias[n];
#pragma unroll
            for (int r = 0; r < 4; ++r)
                outp[(size_t)(mbase + r) * N + n] = acc[i][j][r] + bb;
        }
    }
}

// ---------------- flash attention v10: 1-wave blocks, private LDS, NO barriers ----
// 2048 blocks x 64 threads, 32 q/wave, KVBLK=32 (64 iters). K (32x64) and V~ (64x32)
// tiles double-buffered in 16KB private LDS via pre-swizzled gload_lds (4+4 per iter).
// Pipeline gates are per-wave only: vmcnt(8) keeps current iter's 8 loads in flight
// while waiting the previous tile; lgkmcnt(0) retires reads before next overwrite
// (exact R9 GEMM skeleton, correctness-proven). 8 blocks/CU resident, fully de-phased
// (no s_barrier anywhere). P in registers (permuted k-order baked into Vt, 32-aligned
// so KVBLK=32 reuses it). exp2-domain via builtin, ones-MFMA lsum.
__global__ __launch_bounds__(64) void attn_kernel(
    const u16* __restrict__ Q, const u16* __restrict__ Kb,
    const u16* __restrict__ Vt, u16* __restrict__ Mo)
{
    __shared__ __align__(16) u16 Ksm[2][2048];   // [32 k-rows][64 d] swizzled
    __shared__ __align__(16) u16 Vsm[2][2048];   // [64 d-rows][32 pos] swizzled
    const int lane = threadIdx.x;
    const int r15 = lane & 15, g = lane >> 4;
    // XCD swizzle: each XCD serves 4 consecutive (b,h)
    const int bid = blockIdx.x;
    const int l = (bid & 7) * 256 + (bid >> 3);
    const int bh = l >> 6;
    const int b = bh >> 4, h = bh & 15;
    const int q0 = (l & 63) * 32;

    // persistent Q fragments: q = q0 + qt*16 + r15, d = f*32 + g*8
    const u16* Qbase = Q + ((size_t)b * 2048 + q0) * 1024 + h * 64;
    short8 qf[2][2];
#pragma unroll
    for (int qt = 0; qt < 2; ++qt)
#pragma unroll
        for (int f = 0; f < 2; ++f)
            qf[qt][f] = *(const short8*)(Qbase + (size_t)(qt * 16 + r15) * 1024 + f * 32 + g * 8);

    // staging sources (pre-swizzled). K tile: 256 chunks (32 rows x 8); V: 256 (64 x 4).
    const u16* Ks[4];
    const u16* Vs[4];
#pragma unroll
    for (int j = 0; j < 4; ++j) {
        const int ck = j * 64 + lane;
        const int krow = ck >> 3, kslot = (ck & 7) ^ (krow & 7);
        Ks[j] = Kb + ((size_t)b * 2048 + krow) * 1024 + h * 64 + kslot * 8;
        const int cv = j * 64 + lane;
        const int vrow = cv >> 2, vslot = (cv & 3) ^ (vrow & 3);
        Vs[j] = Vt + ((size_t)b << 21) + (size_t)(h * 64 + vrow) * 2048 + vslot * 8;
    }

    // fragment read bases (swizzled)
    const u16* kbas = &Ksm[0][0] + r15 * 64;     // + (kt*16)*64 + ((f*4+g)^(r15&7))*8
    const int ksl0 = ((g) ^ (r15 & 7)) * 8;
    const int ksl1 = ((4 + g) ^ (r15 & 7)) * 8;
    const u16* vbas = &Vsm[0][0] + r15 * 32 + ((g ^ (r15 & 3)) * 8);  // + (d4*16)*32

    f32x4 acc[2][4];
#pragma unroll
    for (int qt = 0; qt < 2; ++qt)
#pragma unroll
        for (int d4 = 0; d4 < 4; ++d4) acc[qt][d4] = (f32x4){0.f, 0.f, 0.f, 0.f};
    f32x4 accl[2] = {(f32x4){0.f, 0.f, 0.f, 0.f}, (f32x4){0.f, 0.f, 0.f, 0.f}};
    const short8 vone = {0x3F80, 0x3F80, 0x3F80, 0x3F80, 0x3F80, 0x3F80, 0x3F80, 0x3F80};

    auto STAGE = [&](int buf) {
#pragma unroll
        for (int j = 0; j < 4; ++j) {
            gload16(Ks[j], &Ksm[buf][j * 512]);
            gload16(Vs[j], &Vsm[buf][j * 512]);
            Ks[j] += 32768;   // +32 k-rows
            Vs[j] += 32;      // +32 positions
        }
    };

    STAGE(0);
    for (int t = 0; t < 64; ++t) {
        const int buf = t & 1;
        if (t < 63) { STAGE(buf ^ 1); VMW8(); }
        else        { VMW0(); }

        short8 kf[2][2], vf[4];
#pragma unroll
        for (int kt = 0; kt < 2; ++kt) {
            kf[kt][0] = *(const short8*)(kbas + buf * 2048 + kt * 1024 + ksl0);
            kf[kt][1] = *(const short8*)(kbas + buf * 2048 + kt * 1024 + ksl1);
        }
#pragma unroll
        for (int d4 = 0; d4 < 4; ++d4)
            vf[d4] = *(const short8*)(vbas + buf * 2048 + d4 * 512);
        LGK0();   // reads retired -> next STAGE may overwrite

        f32x4 st[2][2];
#pragma unroll
        for (int qt = 0; qt < 2; ++qt)
#pragma unroll
            for (int kt = 0; kt < 2; ++kt) {
                f32x4 zz = (f32x4){0.f, 0.f, 0.f, 0.f};
                zz = __builtin_amdgcn_mfma_f32_16x16x32_bf16(kf[kt][0], qf[qt][0], zz, 0, 0, 0);
                zz = __builtin_amdgcn_mfma_f32_16x16x32_bf16(kf[kt][1], qf[qt][1], zz, 0, 0, 0);
                st[qt][kt] = zz;
            }

        u32v4 pA[2];
#pragma unroll
        for (int qt = 0; qt < 2; ++qt) {
            float e0 = EXP2(st[qt][0][0]);
            float e1 = EXP2(st[qt][0][1]);
            float e2 = EXP2(st[qt][0][2]);
            float e3 = EXP2(st[qt][0][3]);
            float e4 = EXP2(st[qt][1][0]);
            float e5 = EXP2(st[qt][1][1]);
            float e6 = EXP2(st[qt][1][2]);
            float e7 = EXP2(st[qt][1][3]);
            pA[qt][0] = pack2bf(e0, e1);
            pA[qt][1] = pack2bf(e2, e3);
            pA[qt][2] = pack2bf(e4, e5);
            pA[qt][3] = pack2bf(e6, e7);
        }

        accl[0] = __builtin_amdgcn_mfma_f32_16x16x32_bf16(vone, __builtin_bit_cast(short8, pA[0]), accl[0], 0, 0, 0);
        accl[1] = __builtin_amdgcn_mfma_f32_16x16x32_bf16(vone, __builtin_bit_cast(short8, pA[1]), accl[1], 0, 0, 0);

#pragma unroll
        for (int d4 = 0; d4 < 4; ++d4) {
            acc[0][d4] = __builtin_amdgcn_mfma_f32_16x16x32_bf16(vf[d4], __builtin_bit_cast(short8, pA[0]), acc[0][d4], 0, 0, 0);
            acc[1][d4] = __builtin_amdgcn_mfma_f32_16x16x32_bf16(vf[d4], __builtin_bit_cast(short8, pA[1]), acc[1][d4], 0, 0, 0);
        }
    }

#pragma unroll
    for (int qt = 0; qt < 2; ++qt) {
        const float inv = 1.f / accl[qt][0];
        const size_t orow = ((size_t)b * 2048 + q0 + qt * 16 + r15) * 1024 + h * 64;
#pragma unroll
        for (int d4 = 0; d4 < 4; ++d4) {
            uint2 o;
            o.x = pack2bf(acc[qt][d4][0] * inv, acc[qt][d4][1] * inv);
            o.y = pack2bf(acc[qt][d4][2] * inv, acc[qt][d4][3] * inv);
            *(uint2*)(Mo + orow + d4 * 16 + g * 4) = o;
        }
    }
}

extern "C" void kernel_launch(void* const* d_in, const int* in_sizes, int n_in,
                              void* d_out, int out_size, void* d_ws, size_t ws_size,
                              hipStream_t stream) {
    (void)in_sizes; (void)n_in; (void)out_size; (void)ws_size;
    const float* query = (const float*)d_in[0];
    const float* key   = (const float*)d_in[1];
    const float* value = (const float*)d_in[2];
    const float* q_w = (const float*)d_in[3];
    const float* q_b = (const float*)d_in[4];
    const float* k_w = (const float*)d_in[5];
    const float* k_b = (const float*)d_in[6];
    const float* v_w = (const float*)d_in[7];
    const float* v_b = (const float*)d_in[8];
    const float* o_w = (const float*)d_in[9];
    const float* o_b = (const float*)d_in[10];

    const size_t NE = (size_t)4096 * 1024;
    const size_t MW = (size_t)1024 * 1024;
    u16* w = (u16*)d_ws;
    u16* Xq = w;
    u16* Xk = Xq + NE;
    u16* Xv = Xk + NE;
    u16* Wq = Xv + NE;
    u16* Wk = Wq + MW;
    u16* Wv = Wk + MW;
    u16* Wo = Wv + MW;
    u16* Qb = Wo + MW;
    u16* Kb = Qb + NE;
    u16* Vt = Kb + NE;      // [B][1024 d][2048 s], s permuted within 32-blocks
    u16* Mo = Vt + NE;

    cast_all_kernel<<<dim3(2048, 7), 256, 0, stream>>>(
        query, key, value, q_w, k_w, v_w, o_w,
        Xq, Xk, Xv, Wq, Wk, Wv, Wo, (int)NE, (int)MW);
    qkv_gemm<<<dim3(8, 32, 3), 256, 0, stream>>>(
        Xq, Xk, Xv, Wq, Wk, Wv, q_b, k_b, v_b, Qb, Kb, Vt);
    attn_kernel<<<dim3(2048), 64, 0, stream>>>(Qb, Kb, Vt, Mo);
    o_gemm<<<dim3(8, 32), 256, 0, stream>>>(Mo, Wo, o_b, (float*)d_out);
}

// Round 17
// 137.468 us; speedup vs baseline: 1.4698x; 1.2026x over previous
//
#include <hip/hip_runtime.h>
#include <hip/hip_bf16.h>

typedef unsigned short u16;
typedef unsigned int u32;
typedef __attribute__((ext_vector_type(8))) short short8;
typedef __attribute__((ext_vector_type(4))) short s16x4;
typedef __attribute__((ext_vector_type(4))) float f32x4;
typedef __attribute__((ext_vector_type(4))) u32 u32v4;

__device__ __forceinline__ u16 f2bf(float f) {
    u32 u = __float_as_uint(f);
    return (u16)((u + 0x7FFFu + ((u >> 16) & 1u)) >> 16);   // RNE
}
__device__ __forceinline__ u32 pack2bf(float a, float b) {
    __hip_bfloat162 h = __float22bfloat162_rn(float2{a, b});
    return *reinterpret_cast<u32*>(&h);
}
#if __has_builtin(__builtin_amdgcn_exp2f)
#define EXP2(x) __builtin_amdgcn_exp2f(x)
#else
#define EXP2(x) exp2f(x)
#endif

__device__ __forceinline__ void gload16(const void* g, void* s) {
    __builtin_amdgcn_global_load_lds(
        (const __attribute__((address_space(1))) void*)g,
        (__attribute__((address_space(3))) void*)s, 16, 0, 0);
}

// ---------------- fused cast: 7 fp32 tensors -> bf16 ----------------
__global__ __launch_bounds__(256) void cast_all_kernel(
    const float* __restrict__ s0, const float* __restrict__ s1, const float* __restrict__ s2,
    const float* __restrict__ s3, const float* __restrict__ s4, const float* __restrict__ s5,
    const float* __restrict__ s6,
    u16* __restrict__ d0, u16* __restrict__ d1, u16* __restrict__ d2,
    u16* __restrict__ d3, u16* __restrict__ d4, u16* __restrict__ d5,
    u16* __restrict__ d6, int nBig, int nSmall)
{
    const int y = blockIdx.y;
    const float* s = y == 0 ? s0 : (y == 1 ? s1 : (y == 2 ? s2 : (y == 3 ? s3 : (y == 4 ? s4 : (y == 5 ? s5 : s6)))));
    u16* d = y == 0 ? d0 : (y == 1 ? d1 : (y == 2 ? d2 : (y == 3 ? d3 : (y == 4 ? d4 : (y == 5 ? d5 : d6)))));
    const int n = (y < 3) ? nBig : nSmall;
    int i = (blockIdx.x * 256 + threadIdx.x) * 4;
    const int stride = gridDim.x * 256 * 4;
    for (; i < n; i += stride) {
        float4 v = *(const float4*)(s + i);
        uint2 t;
        t.x = pack2bf(v.x, v.y);
        t.y = pack2bf(v.z, v.w);
        *(uint2*)(d + i) = t;
    }
}

// ---------------- fused QKV GEMM (R11 loop; K/V epilogues write fragment-major) ----
// z=0 (Q): bf16 row-major, scaled by 0.125*log2e.
// z=1 (K): fragment-major Kf[(b*16+h)*32 + t][kt*2+f][lane=gk*16+r15k][e]
//          holding K[t*64+kt*16+r15k][h*64+f*32+gk*8+e]  (matches v5 fragment content)
// z=2 (V): fragment-major Vf[(b*16+h)*32 + t][d4*2+kk][lane=g*16+r15v][e]
//          with P's permuted k-order baked in: k = kk*32 + blk*4 + (e&3), pb=2g+(e>>2)
__global__ __launch_bounds__(256) void qkv_gemm(
    const u16* __restrict__ Xq, const u16* __restrict__ Xk, const u16* __restrict__ Xv,
    const u16* __restrict__ Wq, const u16* __restrict__ Wk, const u16* __restrict__ Wv,
    const float* __restrict__ qb, const float* __restrict__ kb, const float* __restrict__ vb,
    u16* __restrict__ Qo, u16* __restrict__ Ko, u16* __restrict__ Vo)
{
    constexpr int N = 1024, K = 1024;
    __shared__ __align__(16) u16 Asm[2][4096];
    __shared__ __align__(16) u16 Bsm[2][4096];
    const int z = blockIdx.z;
    const u16* A = z == 0 ? Xq : (z == 1 ? Xk : Xv);
    const u16* W = z == 0 ? Wq : (z == 1 ? Wk : Wv);
    const float* bias = z == 0 ? qb : (z == 1 ? kb : vb);

    const int tid = threadIdx.x;
    const int wid = tid >> 6;
    const int lane = tid & 63;
    const int r15 = lane & 15, g = lane >> 4;
    const int fb = blockIdx.y * 8 + blockIdx.x;
    const int lsw = (fb & 7) * 32 + (fb >> 3);
    const int m0 = (lsw >> 3) * 128, n0 = (lsw & 7) * 128;
    const int wr = wid >> 1, wc = wid & 1;

    f32x4 acc[4][4];
#pragma unroll
    for (int i = 0; i < 4; ++i)
#pragma unroll
        for (int j = 0; j < 4; ++j) acc[i][j] = (f32x4){0.f, 0.f, 0.f, 0.f};

    const int idx0 = tid, idx1 = tid + 256;
    const size_t aoff0 = (size_t)(m0 + (idx0 >> 2)) * K + (idx0 & 3) * 8;
    const size_t aoff1 = (size_t)(m0 + (idx1 >> 2)) * K + (idx1 & 3) * 8;
    const size_t boff0 = (size_t)(n0 + (idx0 >> 2)) * K + (idx0 & 3) * 8;
    const size_t boff1 = (size_t)(n0 + (idx1 >> 2)) * K + (idx1 & 3) * 8;

    auto STAGE = [&](int buf, int kt) {
        gload16(A + aoff0 + kt, &Asm[buf][wid * 512]);
        gload16(A + aoff1 + kt, &Asm[buf][2048 + wid * 512]);
        gload16(W + boff0 + kt, &Bsm[buf][wid * 512]);
        gload16(W + boff1 + kt, &Bsm[buf][2048 + wid * 512]);
    };

    STAGE(0, 0);
    __syncthreads();
    for (int t = 0; t < 32; ++t) {
        const int buf = t & 1;
        if (t < 31) STAGE(buf ^ 1, (t + 1) * 32);
        short8 af[4], bfr[4];
#pragma unroll
        for (int i = 0; i < 4; ++i) {
            af[i]  = *(const short8*)(&Asm[buf][0] + (wr * 64 + i * 16 + r15) * 32 + g * 8);
            bfr[i] = *(const short8*)(&Bsm[buf][0] + (wc * 64 + i * 16 + r15) * 32 + g * 8);
        }
#pragma unroll
        for (int i = 0; i < 4; ++i)
#pragma unroll
            for (int j = 0; j < 4; ++j)
                acc[i][j] = __builtin_amdgcn_mfma_f32_16x16x32_bf16(af[i], bfr[j], acc[i][j], 0, 0, 0);
        __syncthreads();
    }

    const float scale = (z == 0) ? 0.125f * 1.4426950408889634f : 1.0f;
#pragma unroll
    for (int i = 0; i < 4; ++i) {
        const int mbase = m0 + wr * 64 + i * 16 + g * 4;
#pragma unroll
        for (int j = 0; j < 4; ++j) {
            const int n = n0 + wc * 64 + j * 16 + r15;
            const float bb = bias[n];
            if (z == 0) {
#pragma unroll
                for (int r = 0; r < 4; ++r)
                    Qo[(size_t)(mbase + r) * N + n] = f2bf((acc[i][j][r] + bb) * scale);
            } else if (z == 1) {
                // fragment-major K
                const int b_ = mbase >> 11;
                const int kbase = mbase & 2047;              // k for r=0; low 4 bits vary only
                const int dd = n & 63, hh = n >> 6;
                const int f = dd >> 5, gk = (dd >> 3) & 3, e = dd & 7;
                const size_t tilebase =
                    (((size_t)(b_ * 16 + hh) * 32 + (kbase >> 6)) * 8 + ((kbase >> 4) & 3) * 2 + f) * 512
                    + (size_t)gk * 128 + e;
#pragma unroll
                for (int r = 0; r < 4; ++r)
                    Ko[tilebase + (size_t)((kbase & 15) + r) * 8] = f2bf(acc[i][j][r] + bb);
            } else {
                // fragment-major V with permuted k-order
                const int b_ = mbase >> 11, s_ = mbase & 2047;
                const int t_ = s_ >> 6, kk = (s_ >> 5) & 1;
                const int blk = (s_ >> 2) & 7;
                const int pb = ((blk & 3) << 1) | (blk >> 2);
                const int dd = n & 63, hh = n >> 6;
                const int d4 = dd >> 4, r15v = dd & 15;
                const size_t addr =
                    (((size_t)(b_ * 16 + hh) * 32 + t_) * 8 + d4 * 2 + kk) * 512
                    + (size_t)((pb >> 1) * 16 + r15v) * 8 + (pb & 1) * 4;
                s16x4 pk;
#pragma unroll
                for (int r = 0; r < 4; ++r) pk[r] = (short)f2bf(acc[i][j][r] + bb);
                *(s16x4*)(Vo + addr) = pk;
            }
        }
    }
}

// ---------------- O projection GEMM (R11 form, unchanged/passing) ----------------
__global__ __launch_bounds__(256) void o_gemm(
    const u16* __restrict__ A, const u16* __restrict__ W,
    const float* __restrict__ bias, float* __restrict__ outp)
{
    constexpr int N = 1024, K = 1024;
    __shared__ __align__(16) u16 Asm[2][4096];
    __shared__ __align__(16) u16 Bsm[2][4096];
    const int tid = threadIdx.x;
    const int wid = tid >> 6;
    const int lane = tid & 63;
    const int r15 = lane & 15, g = lane >> 4;
    const int fb = blockIdx.y * 8 + blockIdx.x;
    const int lsw = (fb & 7) * 32 + (fb >> 3);
    const int m0 = (lsw >> 3) * 128, n0 = (lsw & 7) * 128;
    const int wr = wid >> 1, wc = wid & 1;

    f32x4 acc[4][4];
#pragma unroll
    for (int i = 0; i < 4; ++i)
#pragma unroll
        for (int j = 0; j < 4; ++j) acc[i][j] = (f32x4){0.f, 0.f, 0.f, 0.f};

    const int idx0 = tid, idx1 = tid + 256;
    const size_t aoff0 = (size_t)(m0 + (idx0 >> 2)) * K + (idx0 & 3) * 8;
    const size_t aoff1 = (size_t)(m0 + (idx1 >> 2)) * K + (idx1 & 3) * 8;
    const size_t boff0 = (size_t)(n0 + (idx0 >> 2)) * K + (idx0 & 3) * 8;
    const size_t boff1 = (size_t)(n0 + (idx1 >> 2)) * K + (idx1 & 3) * 8;

    auto STAGE = [&](int buf, int kt) {
        gload16(A + aoff0 + kt, &Asm[buf][wid * 512]);
        gload16(A + aoff1 + kt, &Asm[buf][2048 + wid * 512]);
        gload16(W + boff0 + kt, &Bsm[buf][wid * 512]);
        gload16(W + boff1 + kt, &Bsm[buf][2048 + wid * 512]);
    };

    STAGE(0, 0);
    __syncthreads();
    for (int t = 0; t < 32; ++t) {
        const int buf = t & 1;
        if (t < 31) STAGE(buf ^ 1, (t + 1) * 32);
        short8 af[4], bfr[4];
#pragma unroll
        for (int i = 0; i < 4; ++i) {
            af[i]  = *(const short8*)(&Asm[buf][0] + (wr * 64 + i * 16 + r15) * 32 + g * 8);
            bfr[i] = *(const short8*)(&Bsm[buf][0] + (wc * 64 + i * 16 + r15) * 32 + g * 8);
        }
#pragma unroll
        for (int i = 0; i < 4; ++i)
#pragma unroll
            for (int j = 0; j < 4; ++j)
                acc[i][j] = __builtin_amdgcn_mfma_f32_16x16x32_bf16(af[i], bfr[j], acc[i][j], 0, 0, 0);
        __syncthreads();
    }

#pragma unroll
    for (int i = 0; i < 4; ++i) {
        const int mbase = m0 + wr * 64 + i * 16 + g * 4;
#pragma unroll
        for (int j = 0; j < 4; ++j) {
            const int n = n0 + wc * 64 + j * 16 + r15;
            const float bb = bias[n];
#pragma unroll
            for (int r = 0; r < 4; ++r)
                outp[(size_t)(mbase + r) * N + n] = acc[i][j][r] + bb;
        }
    }
}

// ---------------- flash attention v11: fragment-major K/V, no LDS, no barriers ----
// 2048 blocks x 64 threads (1 wave), 32 q/wave. Every K/V fragment load is
// base + lane*16B -> one coalesced global_load_dwordx4, L2-served (2MB per XCD's
// 4 (b,h) pairs). No LDS, no s_barrier, no inline asm, builtin exp2 (R15-proven
// skeleton). P in registers (k-order baked into Vf). ones-MFMA lsum.
__global__ __launch_bounds__(64) void attn_kernel(
    const u16* __restrict__ Q, const u16* __restrict__ Kf,
    const u16* __restrict__ Vf, u16* __restrict__ Mo)
{
    const int lane = threadIdx.x;
    const int r15 = lane & 15, g = lane >> 4;
    // XCD swizzle: each XCD serves 4 consecutive (b,h)
    const int bid = blockIdx.x;
    const int l = (bid & 7) * 256 + (bid >> 3);
    const int bh = l >> 6;
    const int b = bh >> 4, h = bh & 15;
    const int q0 = (l & 63) * 32;

    // persistent Q fragments: q = q0 + qt*16 + r15, d = f*32 + g*8
    const u16* Qbase = Q + ((size_t)b * 2048 + q0) * 1024 + h * 64;
    short8 qf[2][2];
#pragma unroll
    for (int qt = 0; qt < 2; ++qt)
#pragma unroll
        for (int f = 0; f < 2; ++f)
            qf[qt][f] = *(const short8*)(Qbase + (size_t)(qt * 16 + r15) * 1024 + f * 32 + g * 8);

    // fragment-major bases: (b,h) holds 32 tiles x 8 subfrags x 512 u16
    const u16* KfB = Kf + (size_t)bh * (32 * 4096) + lane * 8;
    const u16* VfB = Vf + (size_t)bh * (32 * 4096) + lane * 8;

    f32x4 acc[2][4];
#pragma unroll
    for (int qt = 0; qt < 2; ++qt)
#pragma unroll
        for (int d4 = 0; d4 < 4; ++d4) acc[qt][d4] = (f32x4){0.f, 0.f, 0.f, 0.f};
    f32x4 accl[2] = {(f32x4){0.f, 0.f, 0.f, 0.f}, (f32x4){0.f, 0.f, 0.f, 0.f}};
    const short8 vone = {0x3F80, 0x3F80, 0x3F80, 0x3F80, 0x3F80, 0x3F80, 0x3F80, 0x3F80};

#pragma unroll 2
    for (int t = 0; t < 32; ++t) {
        const u16* Kt = KfB + t * 4096;
        const u16* Vt_ = VfB + t * 4096;
        short8 kf[4][2], vf[4][2];
#pragma unroll
        for (int kt = 0; kt < 4; ++kt) {
            kf[kt][0] = *(const short8*)(Kt + kt * 1024);
            kf[kt][1] = *(const short8*)(Kt + kt * 1024 + 512);
        }
#pragma unroll
        for (int d4 = 0; d4 < 4; ++d4) {
            vf[d4][0] = *(const short8*)(Vt_ + d4 * 1024);
            vf[d4][1] = *(const short8*)(Vt_ + d4 * 1024 + 512);
        }

        f32x4 st[2][4];
#pragma unroll
        for (int qt = 0; qt < 2; ++qt)
#pragma unroll
            for (int kt = 0; kt < 4; ++kt) {
                f32x4 zz = (f32x4){0.f, 0.f, 0.f, 0.f};
                zz = __builtin_amdgcn_mfma_f32_16x16x32_bf16(kf[kt][0], qf[qt][0], zz, 0, 0, 0);
                zz = __builtin_amdgcn_mfma_f32_16x16x32_bf16(kf[kt][1], qf[qt][1], zz, 0, 0, 0);
                st[qt][kt] = zz;
            }

        u32v4 pA[2], pB[2];
#pragma unroll
        for (int qt = 0; qt < 2; ++qt) {
#pragma unroll
            for (int kt = 0; kt < 4; ++kt) {
                float e0 = EXP2(st[qt][kt][0]);
                float e1 = EXP2(st[qt][kt][1]);
                float e2 = EXP2(st[qt][kt][2]);
                float e3 = EXP2(st[qt][kt][3]);
                u32 lo = pack2bf(e0, e1);
                u32 hi = pack2bf(e2, e3);
                if (kt < 2) { pA[qt][kt * 2] = lo; pA[qt][kt * 2 + 1] = hi; }
                else        { pB[qt][(kt - 2) * 2] = lo; pB[qt][(kt - 2) * 2 + 1] = hi; }
            }
        }

        accl[0] = __builtin_amdgcn_mfma_f32_16x16x32_bf16(vone, __builtin_bit_cast(short8, pA[0]), accl[0], 0, 0, 0);
        accl[0] = __builtin_amdgcn_mfma_f32_16x16x32_bf16(vone, __builtin_bit_cast(short8, pB[0]), accl[0], 0, 0, 0);
        accl[1] = __builtin_amdgcn_mfma_f32_16x16x32_bf16(vone, __builtin_bit_cast(short8, pA[1]), accl[1], 0, 0, 0);
        accl[1] = __builtin_amdgcn_mfma_f32_16x16x32_bf16(vone, __builtin_bit_cast(short8, pB[1]), accl[1], 0, 0, 0);

#pragma unroll
        for (int d4 = 0; d4 < 4; ++d4) {
            acc[0][d4] = __builtin_amdgcn_mfma_f32_16x16x32_bf16(vf[d4][0], __builtin_bit_cast(short8, pA[0]), acc[0][d4], 0, 0, 0);
            acc[0][d4] = __builtin_amdgcn_mfma_f32_16x16x32_bf16(vf[d4][1], __builtin_bit_cast(short8, pB[0]), acc[0][d4], 0, 0, 0);
            acc[1][d4] = __builtin_amdgcn_mfma_f32_16x16x32_bf16(vf[d4][0], __builtin_bit_cast(short8, pA[1]), acc[1][d4], 0, 0, 0);
            acc[1][d4] = __builtin_amdgcn_mfma_f32_16x16x32_bf16(vf[d4][1], __builtin_bit_cast(short8, pB[1]), acc[1][d4], 0, 0, 0);
        }
    }

#pragma unroll
    for (int qt = 0; qt < 2; ++qt) {
        const float inv = 1.f / accl[qt][0];
        const size_t orow = ((size_t)b * 2048 + q0 + qt * 16 + r15) * 1024 + h * 64;
#pragma unroll
        for (int d4 = 0; d4 < 4; ++d4) {
            uint2 o;
            o.x = pack2bf(acc[qt][d4][0] * inv, acc[qt][d4][1] * inv);
            o.y = pack2bf(acc[qt][d4][2] * inv, acc[qt][d4][3] * inv);
            *(uint2*)(Mo + orow + d4 * 16 + g * 4) = o;
        }
    }
}

extern "C" void kernel_launch(void* const* d_in, const int* in_sizes, int n_in,
                              void* d_out, int out_size, void* d_ws, size_t ws_size,
                              hipStream_t stream) {
    (void)in_sizes; (void)n_in; (void)out_size; (void)ws_size;
    const float* query = (const float*)d_in[0];
    const float* key   = (const float*)d_in[1];
    const float* value = (const float*)d_in[2];
    const float* q_w = (const float*)d_in[3];
    const float* q_b = (const float*)d_in[4];
    const float* k_w = (const float*)d_in[5];
    const float* k_b = (const float*)d_in[6];
    const float* v_w = (const float*)d_in[7];
    const float* v_b = (const float*)d_in[8];
    const float* o_w = (const float*)d_in[9];
    const float* o_b = (const float*)d_in[10];

    const size_t NE = (size_t)4096 * 1024;
    const size_t MW = (size_t)1024 * 1024;
    u16* w = (u16*)d_ws;
    u16* Xq = w;
    u16* Xk = Xq + NE;
    u16* Xv = Xk + NE;
    u16* Wq = Xv + NE;
    u16* Wk = Wq + MW;
    u16* Wv = Wk + MW;
    u16* Wo = Wv + MW;
    u16* Qb = Wo + MW;
    u16* Kf = Qb + NE;      // fragment-major K: [(b*16+h)*32+t][8 subfrags][64 lanes][8]
    u16* Vf = Kf + NE;      // fragment-major V~ (permuted k-order)
    u16* Mo = Vf + NE;

    cast_all_kernel<<<dim3(2048, 7), 256, 0, stream>>>(
        query, key, value, q_w, k_w, v_w, o_w,
        Xq, Xk, Xv, Wq, Wk, Wv, Wo, (int)NE, (int)MW);
    qkv_gemm<<<dim3(8, 32, 3), 256, 0, stream>>>(
        Xq, Xk, Xv, Wq, Wk, Wv, q_b, k_b, v_b, Qb, Kf, Vf);
    attn_kernel<<<dim3(2048), 64, 0, stream>>>(Qb, Kf, Vf, Mo);
    o_gemm<<<dim3(8, 32), 256, 0, stream>>>(Mo, Wo, o_b, (float*)d_out);
}